// Round 3
// baseline (242.712 us; speedup 1.0000x reference)
//
#include <hip/hip_runtime.h>

// EMA along T for pos_seq (B=64, T=8192, C=51) fp32.
// y[b,0,c] = x[b,0,c];  y[b,t,c] = 0.25*x[b,t,c] + 0.75*y[b,t-1,c]
//
// R2 post-mortem: CHUNK_L=32 < HALO_H=48 made chunk 1 read x[t0-48] = x[-16]
// -> OOB read -> core dump. Fix: clamp halo start at t=0 (h = min(H, t0));
// when clamped, seed x[0] == y[0] exactly, so truncation error only shrinks.
//
// Occupancy theory (R1): 25% occ / 29% HBM / VALU 2.7% = latency-bound on
// grid size. CHUNK_L 128->32 gives 835,584 threads = 51 waves/CU offered
// (caps at HW 32). Halo re-reads (2.5x logical) absorbed by L2/L3.

#define EMA_ALPHA 0.25f
#define EMA_BETA  0.75f
#define T_DIM 8192
#define C_DIM 51
#define CHUNK_L 32
#define HALO_H  48
#define NCHUNK (T_DIM / CHUNK_L)   // 256

__global__ __launch_bounds__(256) void ema_kernel(const float* __restrict__ x,
                                                  float* __restrict__ y,
                                                  int total_threads) {
    int gid = blockIdx.x * blockDim.x + threadIdx.x;
    if (gid >= total_threads) return;

    int c = gid % C_DIM;
    int rest = gid / C_DIM;
    int chunk = rest % NCHUNK;
    int b = rest / NCHUNK;

    const size_t seq_base = (size_t)b * T_DIM * C_DIM + c;
    const float* __restrict__ xb = x + seq_base;
    float* __restrict__ yb = y + seq_base;

    const int t0 = chunk * CHUNK_L;
    float acc;
    int tstart;

    if (chunk == 0) {
        // exact start
        acc = xb[0];
        yb[0] = acc;
        tstart = 1;
    } else {
        // halo warm-up, clamped at t=0: h = min(HALO_H, t0) >= 32.
        // Seed with x[th]; if th==0 the seed equals y[0] exactly.
        const int h = (t0 < HALO_H) ? t0 : HALO_H;
        const int th = t0 - h;
        acc = xb[(size_t)th * C_DIM];
        for (int i = 1; i < h; ++i) {
            float xv = xb[(size_t)(th + i) * C_DIM];
            acc = fmaf(EMA_ALPHA, xv, EMA_BETA * acc);
        }
        tstart = t0;
    }

    const int tend = t0 + CHUNK_L;
#pragma unroll 8
    for (int t = tstart; t < tend; ++t) {
        float xv = xb[(size_t)t * C_DIM];
        acc = fmaf(EMA_ALPHA, xv, EMA_BETA * acc);
        yb[(size_t)t * C_DIM] = acc;
    }
}

extern "C" void kernel_launch(void* const* d_in, const int* in_sizes, int n_in,
                              void* d_out, int out_size, void* d_ws, size_t ws_size,
                              hipStream_t stream) {
    const float* x = (const float*)d_in[0];
    float* y = (float*)d_out;

    int B = in_sizes[0] / (T_DIM * C_DIM);   // 64
    int total = B * NCHUNK * C_DIM;          // 835584
    int block = 256;
    int grid = (total + block - 1) / block;  // 3264

    ema_kernel<<<grid, block, 0, stream>>>(x, y, total);
}

// Round 4
// 211.044 us; speedup vs baseline: 1.1501x; 1.1501x over previous
//
#include <hip/hip_runtime.h>

// EMA along T for pos_seq (B=64, T=8192, C=51) fp32.
// y[b,0,c] = x[b,0,c];  y[b,t,c] = 0.25*x[b,t,c] + 0.75*y[b,t-1,c]
//
// R3 post-mortem: variable-length halo loop -> no unroll -> VGPR 12 -> only
// ~3 loads in flight/wave; BW stuck at 2.5 TB/s despite 68% occupancy.
// Model: BW ~ occupancy x loads-in-flight-per-wave (R1 700 vs R3 816 units
// matched the 1.07x BW ratio).
//
// R4: everything fixed-trip-count so the compiler unrolls & batches loads.
//  - halo: always exactly 48 steps, read index clamped to >=0. With L=64,
//    only chunk 0 clamps, and there the halo is a fixed point
//    (0.25*x0 + 0.75*x0 == x0), so seeding is exact -> NO branch at all;
//    main loop always 64 steps (y[0] = x0 via the same fixed point).
//  - L=64: 417,792 threads = 25.5 waves/CU offered (~80% occ), 1.75x logical
//    read amplification absorbed by L2/L3 (input persists in 256MB L3).
//  - __launch_bounds__(256,8): cap 64 VGPR, still 8 waves/SIMD.
//  - nontemporal stores: keep the 107MB write stream out of L2/L3.

#define EMA_ALPHA 0.25f
#define EMA_BETA  0.75f
#define T_DIM 8192
#define C_DIM 51
#define CHUNK_L 64
#define HALO_H  48
#define NCHUNK (T_DIM / CHUNK_L)   // 128

__global__ __launch_bounds__(256, 8) void ema_kernel(const float* __restrict__ x,
                                                     float* __restrict__ y,
                                                     int total_threads) {
    int gid = blockIdx.x * blockDim.x + threadIdx.x;
    if (gid >= total_threads) return;

    int c = gid % C_DIM;
    int rest = gid / C_DIM;
    int chunk = rest % NCHUNK;
    int b = rest / NCHUNK;

    const size_t seq_base = (size_t)b * T_DIM * C_DIM + c;
    const float* __restrict__ xb = x + seq_base;
    float* __restrict__ yb = y + seq_base;

    const int t0 = chunk * CHUNK_L;
    const int th = t0 - HALO_H;   // may be negative only for chunk 0

    // Seed + fixed 48-step halo warm-up, indices clamped to >= 0.
    // chunk 0: all clamp to 0, acc stays exactly x[0] (fixed point).
    int i0 = th < 0 ? 0 : th;
    float acc = xb[(size_t)i0 * C_DIM];
#pragma unroll
    for (int i = 1; i < HALO_H; ++i) {
        int ti = th + i;
        ti = ti < 0 ? 0 : ti;
        float xv = xb[(size_t)ti * C_DIM];
        acc = fmaf(EMA_ALPHA, xv, EMA_BETA * acc);
    }

    // Main loop: always exactly CHUNK_L steps from t0.
    // chunk 0, t=0: 0.25*x0 + 0.75*x0 == x0 == y[0]. Exact.
#pragma unroll
    for (int j = 0; j < CHUNK_L; ++j) {
        const int t = t0 + j;
        float xv = xb[(size_t)t * C_DIM];
        acc = fmaf(EMA_ALPHA, xv, EMA_BETA * acc);
        __builtin_nontemporal_store(acc, &yb[(size_t)t * C_DIM]);
    }
}

extern "C" void kernel_launch(void* const* d_in, const int* in_sizes, int n_in,
                              void* d_out, int out_size, void* d_ws, size_t ws_size,
                              hipStream_t stream) {
    const float* x = (const float*)d_in[0];
    float* y = (float*)d_out;

    int B = in_sizes[0] / (T_DIM * C_DIM);   // 64
    int total = B * NCHUNK * C_DIM;          // 417792
    int block = 256;
    int grid = (total + block - 1) / block;  // 1632

    ema_kernel<<<grid, block, 0, stream>>>(x, y, total);
}

// Round 6
// 190.572 us; speedup vs baseline: 1.2736x; 1.1074x over previous
//
#include <hip/hip_runtime.h>

// EMA along T for pos_seq (B=64, T=8192, C=51) fp32.
// y[b,0,c] = x[b,0,c];  y[b,t,c] = 0.25*x[b,t,c] + 0.75*y[b,t-1,c]
//
// R5 post-mortem: compile error only — __builtin_nontemporal_store requires
// a clang vector type, not HIP's float4 class. R6 = R5 with a native
// ext_vector_type(4) float used for all 16B moves. Theory unchanged:
//
// R4 showed BW pinned at ~2.4-2.5 TB/s across occupancy 25/39/68% -> the
// scalar-dword (4B/lane) streaming plateau (guide m18: 2.35 TB/s scalar vs
// 4.89 TB/s at 16B/lane). Per-thread t-stride (204B) forbids vector access,
// so restructure around LDS:
//
//  Block (256 thr) = (b, 128-row T-chunk). Tile = 48 halo + 128 rows.
//  48*51 and 128*51 are multiples of 4 floats -> tile & output segments are
//  16B-aligned contiguous runs, no remainder.
//   P1: v4-stage 176x51 tile -> LDS (chunk 0: rows<0 staged as row 0, halo
//       becomes fixed point => exact).
//   P2: 204 threads (c=tid%51, sub=tid/51): 48-step halo warm-up from LDS.
//   P3: 32-step main EMA in-place in LDS (own cells; barrier protects
//       neighbors' halo reads).
//   P4: v4 nontemporal store of rows 48..175.
// All HBM traffic is dwordx4 streaming (m13 pattern, 6.29 TB/s ceiling).

typedef float vfloat4 __attribute__((ext_vector_type(4)));

#define T_DIM 8192
#define C_DIM 51
#define L_ROWS 128
#define H_ROWS 48
#define TILE_ROWS (L_ROWS + H_ROWS)          // 176
#define TILE_ELEMS (TILE_ROWS * C_DIM)       // 8976 floats = 35904 B LDS
#define OUT_ELEMS (L_ROWS * C_DIM)           // 6528
#define SUB_LEN 32
#define NSUB 4                               // 4 x 51 = 204 compute threads
#define NCHUNK (T_DIM / L_ROWS)              // 64

__global__ __launch_bounds__(256, 4) void ema_kernel(const float* __restrict__ x,
                                                     float* __restrict__ y) {
    __shared__ float tile[TILE_ELEMS];

    const int tid = threadIdx.x;
    const int chunk = blockIdx.x % NCHUNK;
    const int b = blockIdx.x / NCHUNK;
    const size_t plane = (size_t)b * ((size_t)T_DIM * C_DIM);
    const int t0 = chunk * L_ROWS;
    const int start_f = (t0 - H_ROWS) * C_DIM;   // multiple of 4 (<0 only for chunk 0)

    const float* __restrict__ xp = x + plane;

    // ---- Phase 1: stage tile (16B, fully aligned) ----
    if (chunk != 0) {
        for (int j = tid; j < TILE_ELEMS / 4; j += 256) {
            vfloat4 v = *(const vfloat4*)(xp + start_f + 4 * j);
            *(vfloat4*)(&tile[4 * j]) = v;
        }
    } else {
        // start_f = -2448; e = start_f + 4j is 4-aligned, so a v4 is either
        // fully negative (clamp each elem to row 0) or fully valid.
        for (int j = tid; j < TILE_ELEMS / 4; j += 256) {
            int e = start_f + 4 * j;
            if (e >= 0) {
                *(vfloat4*)(&tile[4 * j]) = *(const vfloat4*)(xp + e);
            } else {
                vfloat4 v;
#pragma unroll
                for (int k = 0; k < 4; ++k) {
                    int c = (e + k + H_ROWS * C_DIM) % C_DIM;  // e+k in [-2448,-1]
                    v[k] = xp[c];                               // row-0 clamp
                }
                *(vfloat4*)(&tile[4 * j]) = v;
            }
        }
    }
    __syncthreads();

    // ---- Phase 2: halo warm-up from LDS (48 fixed steps) ----
    const int c = tid % C_DIM;
    const int sub = tid / C_DIM;
    const bool active = (tid < NSUB * C_DIM);
    float acc = 0.0f;
    if (active) {
        const int tr = sub * SUB_LEN;           // tile row of halo start
        acc = tile[tr * C_DIM + c];
#pragma unroll
        for (int i = 1; i < H_ROWS; ++i)
            acc = fmaf(0.25f, tile[(tr + i) * C_DIM + c], 0.75f * acc);
    }
    __syncthreads();   // halo reads done before in-place overwrite

    // ---- Phase 3: main EMA, in-place in LDS ----
    if (active) {
        const int base = (H_ROWS + sub * SUB_LEN) * C_DIM + c;
#pragma unroll
        for (int i = 0; i < SUB_LEN; ++i) {
            float xv = tile[base + i * C_DIM];
            acc = fmaf(0.25f, xv, 0.75f * acc);
            tile[base + i * C_DIM] = acc;
        }
    }
    __syncthreads();

    // ---- Phase 4: coalesced 16B store of rows 48..175 ----
    float* __restrict__ yp = y + plane + (size_t)t0 * C_DIM;
    for (int j = tid; j < OUT_ELEMS / 4; j += 256) {
        vfloat4 v = *(const vfloat4*)(&tile[H_ROWS * C_DIM + 4 * j]);
        __builtin_nontemporal_store(v, (vfloat4*)(yp + 4 * j));
    }
}

extern "C" void kernel_launch(void* const* d_in, const int* in_sizes, int n_in,
                              void* d_out, int out_size, void* d_ws, size_t ws_size,
                              hipStream_t stream) {
    const float* x = (const float*)d_in[0];
    float* y = (float*)d_out;

    int B = in_sizes[0] / (T_DIM * C_DIM);   // 64
    int grid = B * NCHUNK;                   // 4096 blocks
    ema_kernel<<<grid, 256, 0, stream>>>(x, y);
}